// Round 1
// baseline (482.060 us; speedup 1.0000x reference)
//
#include <hip/hip_runtime.h>
#include <stdint.h>

#define DEV __device__ __forceinline__

typedef __bf16 bf16x8 __attribute__((ext_vector_type(8)));
typedef float f32x4 __attribute__((ext_vector_type(4)));
typedef unsigned short u16;
typedef u16 u16x8 __attribute__((ext_vector_type(8)));

static constexpr int Bb = 8, Tt = 1024, Dd = 1024, Hh = 16;
static constexpr int BT = Bb * Tt;      // 8192
static constexpr int DH2 = 128;         // concat per-head dim

// ---------- helpers ----------
DEV u16 f2bf(float f) {
  uint32_t u = __float_as_uint(f);
  uint32_t r = (u + 0x7FFFu + ((u >> 16) & 1u)) >> 16;
  return (u16)r;
}

DEV void gload_lds16(const void* g, void* lds) {
  __builtin_amdgcn_global_load_lds(
      (const __attribute__((address_space(1))) void*)g,
      (__attribute__((address_space(3))) void*)lds,
      16, 0, 0);
}

// ---------- f32 -> bf16 convert ----------
__global__ __launch_bounds__(256) void k_cvt_bf16(const float* __restrict__ in,
                                                  u16* __restrict__ out, int n8) {
  int i = blockIdx.x * blockDim.x + threadIdx.x;
  int stride = gridDim.x * blockDim.x;
  for (; i < n8; i += stride) {
    const float4* p = reinterpret_cast<const float4*>(in) + (size_t)i * 2;
    float4 a = p[0], b = p[1];
    u16x8 o;
    o[0] = f2bf(a.x); o[1] = f2bf(a.y); o[2] = f2bf(a.z); o[3] = f2bf(a.w);
    o[4] = f2bf(b.x); o[5] = f2bf(b.y); o[6] = f2bf(b.z); o[7] = f2bf(b.w);
    reinterpret_cast<u16x8*>(out)[i] = o;
  }
}

// ---------- GEMM: C[M,N] = A[M,K] @ W[N,K]^T ----------
// AMODE 0: A dense bf16 [m*1024+k].  AMODE 1: A = Obuf head-gather (base pre-offset by slot*64):
//          addr = ((m>>10)*16 + (k>>6))*1024*128 + (m&1023)*128 + (k&63)
// EMODE 0: f32 store dst[m*1024+n] = acc + bias[n]
// EMODE 1: bf16 store to attention layout (base pre-offset by slot*64):
//          ((m>>10)*16 + (n>>6))*1024*128 + (m&1023)*128 + (n&63)
template <int AMODE, int EMODE>
__global__ __launch_bounds__(256) void k_gemm(const u16* __restrict__ A,
                                              const u16* __restrict__ W,
                                              const float* __restrict__ bias,
                                              void* __restrict__ dst) {
  __shared__ alignas(16) u16 As[128 * 32];
  __shared__ alignas(16) u16 Bs[128 * 32];
  const int tid = threadIdx.x;
  const int l = tid & 63;
  const int w = tid >> 6;
  const int m0 = blockIdx.y * 128;
  const int n0 = blockIdx.x * 128;
  const int wr = (w >> 1) * 64, wc = (w & 1) * 64;

  f32x4 acc[4][4] = {};

  for (int kt = 0; kt < 32; ++kt) {
    const int kbase = kt * 32;
#pragma unroll
    for (int rep = 0; rep < 2; ++rep) {
      int chunk = rep * 4 + w;
      int idx = chunk * 64 + l;       // 16B-granule linear index
      int row = idx >> 2;
      int p = idx & 3;
      int g = p ^ ((row >> 1) & 3);   // logical granule for this physical slot
      const u16* asrc;
      if (AMODE == 0) {
        asrc = A + (size_t)(m0 + row) * 1024 + kbase + g * 8;
      } else {
        int m = m0 + row;
        int k = kbase + g * 8;
        asrc = A + ((size_t)((m >> 10) * 16 + (k >> 6)) * 1024 + (m & 1023)) * 128 + (k & 63);
      }
      gload_lds16(asrc, &As[chunk * 512]);
      const u16* bsrc = W + (size_t)(n0 + row) * 1024 + kbase + g * 8;
      gload_lds16(bsrc, &Bs[chunk * 512]);
    }
    __syncthreads();

    bf16x8 af[4], bfr[4];
#pragma unroll
    for (int mi = 0; mi < 4; ++mi) {
      int row = wr + mi * 16 + (l & 15);
      int p = (l >> 4) ^ ((row >> 1) & 3);
      af[mi] = *reinterpret_cast<const bf16x8*>(&As[row * 32 + p * 8]);
    }
#pragma unroll
    for (int ni = 0; ni < 4; ++ni) {
      int row = wc + ni * 16 + (l & 15);
      int p = (l >> 4) ^ ((row >> 1) & 3);
      bfr[ni] = *reinterpret_cast<const bf16x8*>(&Bs[row * 32 + p * 8]);
    }
#pragma unroll
    for (int mi = 0; mi < 4; ++mi)
#pragma unroll
      for (int ni = 0; ni < 4; ++ni)
        acc[mi][ni] = __builtin_amdgcn_mfma_f32_16x16x32_bf16(af[mi], bfr[ni], acc[mi][ni], 0, 0, 0);
    __syncthreads();
  }

#pragma unroll
  for (int mi = 0; mi < 4; ++mi)
#pragma unroll
    for (int ni = 0; ni < 4; ++ni)
#pragma unroll
      for (int j = 0; j < 4; ++j) {
        int row = m0 + wr + mi * 16 + (l >> 4) * 4 + j;
        int col = n0 + wc + ni * 16 + (l & 15);
        float v = acc[mi][ni][j];
        if constexpr (EMODE == 0) {
          ((float*)dst)[(size_t)row * 1024 + col] = v + bias[col];
        } else {
          ((u16*)dst)[((size_t)((row >> 10) * 16 + (col >> 6)) * 1024 + (row & 1023)) * 128 + (col & 63)] = f2bf(v);
        }
      }
}

// ---------- flash attention over concat head-dim 128 ----------
// grid: (T/64, B*H). 4 waves; wave w owns 16 q rows.
__global__ __launch_bounds__(256) void k_attn(const u16* __restrict__ Q,
                                              const u16* __restrict__ K,
                                              const u16* __restrict__ V,
                                              u16* __restrict__ O) {
  __shared__ alignas(16) u16 Ks[32 * 128];   // [kv][d], 256B rows, swz G^(row&7)
  __shared__ alignas(16) u16 Vt[128 * 32];   // [d][kv], 64B rows, swz g^((d>>1)&3)
  __shared__ alignas(16) u16 Pl[4][16 * 32]; // per-wave P, 64B rows, swz g^((q>>1)&3)
  const int tid = threadIdx.x;
  const int l = tid & 63, w = tid >> 6;
  const int bh = blockIdx.y;
  const int q0 = blockIdx.x * 64 + w * 16;
  const size_t base = (size_t)bh * 1024 * 128;

  bf16x8 qf[4];
#pragma unroll
  for (int dc = 0; dc < 4; ++dc)
    qf[dc] = *reinterpret_cast<const bf16x8*>(
        Q + base + (size_t)(q0 + (l & 15)) * 128 + dc * 32 + (l >> 4) * 8);

  float m_run[4], l_run[4];
  f32x4 Oa[8] = {};
#pragma unroll
  for (int j = 0; j < 4; ++j) { m_run[j] = -1e30f; l_run[j] = 0.f; }

  for (int kv0 = 0; kv0 < 1024; kv0 += 32) {
    // stage K chunk via global_load_lds (linear dest, pre-swizzled source)
#pragma unroll
    for (int rep = 0; rep < 2; ++rep) {
      int chunk = rep * 4 + w;
      int row = chunk * 4 + (l >> 4);
      int P = l & 15;
      int G = P ^ (row & 7);
      gload_lds16(K + base + (size_t)(kv0 + row) * 128 + G * 8, &Ks[chunk * 512]);
    }
    // stage V transposed (register path)
    {
      int d = tid & 127;
      int kvh = tid >> 7;   // 0 or 1 -> kv 0..15 / 16..31
      u16 vv[16];
#pragma unroll
      for (int j = 0; j < 16; ++j)
        vv[j] = V[base + (size_t)(kv0 + kvh * 16 + j) * 128 + d];
#pragma unroll
      for (int half = 0; half < 2; ++half) {
        int Gv = kvh * 2 + half;
        int p = Gv ^ ((d >> 1) & 3);
        u16x8 pk;
#pragma unroll
        for (int j = 0; j < 8; ++j) pk[j] = vv[half * 8 + j];
        *reinterpret_cast<u16x8*>(&Vt[d * 32 + p * 8]) = pk;
      }
    }
    __syncthreads();

    // QK^T : S[h2] is 16q x 16kv
    f32x4 S[2];
#pragma unroll
    for (int h2 = 0; h2 < 2; ++h2) {
      f32x4 s = {};
#pragma unroll
      for (int dc = 0; dc < 4; ++dc) {
        int row = h2 * 16 + (l & 15);
        int G = dc * 4 + (l >> 4);
        int P = G ^ (row & 7);
        bf16x8 kb = *reinterpret_cast<const bf16x8*>(&Ks[row * 128 + P * 8]);
        s = __builtin_amdgcn_mfma_f32_16x16x32_bf16(qf[dc], kb, s, 0, 0, 0);
      }
      S[h2] = s;
    }
    const float scale = 0.0625f;  // 0.5 / sqrt(64)
    float alpha[4];
#pragma unroll
    for (int j = 0; j < 4; ++j) {
      float s0 = S[0][j] * scale, s1 = S[1][j] * scale;
      float mx = fmaxf(s0, s1);
#pragma unroll
      for (int off = 1; off < 16; off <<= 1) mx = fmaxf(mx, __shfl_xor(mx, off));
      float mn = fmaxf(m_run[j], mx);
      alpha[j] = __expf(m_run[j] - mn);
      float p0 = __expf(s0 - mn), p1 = __expf(s1 - mn);
      float rs = p0 + p1;
#pragma unroll
      for (int off = 1; off < 16; off <<= 1) rs += __shfl_xor(rs, off);
      l_run[j] = alpha[j] * l_run[j] + rs;
      m_run[j] = mn;
      S[0][j] = p0; S[1][j] = p1;
    }
#pragma unroll
    for (int n = 0; n < 8; ++n)
#pragma unroll
      for (int j = 0; j < 4; ++j) Oa[n][j] *= alpha[j];

    // P (C-layout) -> LDS, to be reread in A-fragment layout
#pragma unroll
    for (int h2 = 0; h2 < 2; ++h2)
#pragma unroll
      for (int j = 0; j < 4; ++j) {
        int q = (l >> 4) * 4 + j;
        int kv = h2 * 16 + (l & 15);
        int p = (kv >> 3) ^ ((q >> 1) & 3);
        Pl[w][q * 32 + p * 8 + (kv & 7)] = f2bf(S[h2][j]);
      }
    __syncthreads();

    // PV: Oa[n] += P(16x32) @ V(32x16-block n)
    {
      int row = l & 15;
      int p = (l >> 4) ^ ((row >> 1) & 3);
      bf16x8 pa = *reinterpret_cast<const bf16x8*>(&Pl[w][row * 32 + p * 8]);
#pragma unroll
      for (int n = 0; n < 8; ++n) {
        int d = n * 16 + (l & 15);
        int pv = (l >> 4) ^ ((d >> 1) & 3);
        bf16x8 vb = *reinterpret_cast<const bf16x8*>(&Vt[d * 32 + pv * 8]);
        Oa[n] = __builtin_amdgcn_mfma_f32_16x16x32_bf16(pa, vb, Oa[n], 0, 0, 0);
      }
    }
    __syncthreads();
  }

#pragma unroll
  for (int j = 0; j < 4; ++j) {
    float inv = 1.0f / l_run[j];
    int row = q0 + (l >> 4) * 4 + j;
#pragma unroll
    for (int n = 0; n < 8; ++n)
      O[base + (size_t)row * 128 + n * 16 + (l & 15)] = f2bf(Oa[n][j] * inv);
  }
}

// ---------- launch ----------
extern "C" void kernel_launch(void* const* d_in, const int* in_sizes, int n_in,
                              void* d_out, int out_size, void* d_ws, size_t ws_size,
                              hipStream_t stream) {
  const float* x   = (const float*)d_in[0];
  const float* y   = (const float*)d_in[1];
  const float* Wq  = (const float*)d_in[2];
  const float* Wk  = (const float*)d_in[3];
  const float* Wv  = (const float*)d_in[4];
  const float* Wox = (const float*)d_in[5];
  const float* box = (const float*)d_in[6];
  const float* Woy = (const float*)d_in[7];
  const float* boy = (const float*)d_in[8];

  u16* ws = (u16*)d_ws;
  size_t off = 0;
  u16* xb  = ws + off; off += (size_t)BT * Dd;
  u16* yb  = ws + off; off += (size_t)BT * Dd;
  u16* Wqb = ws + off; off += (size_t)Dd * Dd;
  u16* Wkb = ws + off; off += (size_t)Dd * Dd;
  u16* Wvb = ws + off; off += (size_t)Dd * Dd;
  u16* Woxb = ws + off; off += (size_t)Dd * Dd;
  u16* Woyb = ws + off; off += (size_t)Dd * Dd;
  const size_t attn_elems = (size_t)Bb * Hh * Tt * DH2;  // 16.78M
  u16* Qb = ws + off; off += attn_elems;
  u16* Kb = ws + off; off += attn_elems;
  u16* Vb = ws + off; off += attn_elems;
  u16* Ob = ws + off; off += attn_elems;

  auto cvt = [&](const float* src, u16* dstp, size_t n) {
    int n8 = (int)(n / 8);
    int blocks = (n8 + 255) / 256;
    if (blocks > 2048) blocks = 2048;
    k_cvt_bf16<<<dim3(blocks), dim3(256), 0, stream>>>(src, dstp, n8);
  };
  cvt(x, xb, (size_t)BT * Dd);
  cvt(y, yb, (size_t)BT * Dd);
  cvt(Wq, Wqb, (size_t)Dd * Dd);
  cvt(Wk, Wkb, (size_t)Dd * Dd);
  cvt(Wv, Wvb, (size_t)Dd * Dd);
  cvt(Wox, Woxb, (size_t)Dd * Dd);
  cvt(Woy, Woyb, (size_t)Dd * Dd);

  dim3 ggrid(8, 64), gblk(256);
  // projections into concat attention layout: slot0 = x-stream, slot1 = y-stream
  k_gemm<0, 1><<<ggrid, gblk, 0, stream>>>(yb, Wqb, nullptr, Qb + 0);   // q_sx = y@Wq^T
  k_gemm<0, 1><<<ggrid, gblk, 0, stream>>>(xb, Wqb, nullptr, Qb + 64);  // q_sy = x@Wq^T
  k_gemm<0, 1><<<ggrid, gblk, 0, stream>>>(xb, Wkb, nullptr, Kb + 0);   // k_sx
  k_gemm<0, 1><<<ggrid, gblk, 0, stream>>>(yb, Wkb, nullptr, Kb + 64);  // k_sy
  k_gemm<0, 1><<<ggrid, gblk, 0, stream>>>(xb, Wvb, nullptr, Vb + 0);   // v_sx
  k_gemm<0, 1><<<ggrid, gblk, 0, stream>>>(yb, Wvb, nullptr, Vb + 64);  // v_sy

  k_attn<<<dim3(16, 128), gblk, 0, stream>>>(Qb, Kb, Vb, Ob);

  float* out1 = (float*)d_out;
  float* out2 = out1 + (size_t)BT * Dd;
  k_gemm<1, 0><<<ggrid, gblk, 0, stream>>>(Ob + 0,  Woxb, box, out1);
  k_gemm<1, 0><<<ggrid, gblk, 0, stream>>>(Ob + 64, Woyb, boy, out2);
}

// Round 2
// 358.664 us; speedup vs baseline: 1.3440x; 1.3440x over previous
//
#include <hip/hip_runtime.h>
#include <stdint.h>

#define DEV __device__ __forceinline__

typedef __bf16 bf16x8 __attribute__((ext_vector_type(8)));
typedef float f32x4 __attribute__((ext_vector_type(4)));
typedef unsigned short u16;
typedef u16 u16x4v __attribute__((ext_vector_type(4)));
typedef u16 u16x8 __attribute__((ext_vector_type(8)));
typedef uint32_t u32;

static constexpr int Bb = 8, Tt = 1024, Dd = 1024, Hh = 16;
static constexpr int BT = Bb * Tt;      // 8192

// ---------- helpers ----------
DEV u16 f2bf(float f) {
  u32 u = __float_as_uint(f);
  u32 r = (u + 0x7FFFu + ((u >> 16) & 1u)) >> 16;
  return (u16)r;
}
DEV u32 pack2(float a, float b) {
  return (u32)f2bf(a) | ((u32)f2bf(b) << 16);
}
DEV void gload_lds16(const void* g, void* lds) {
  __builtin_amdgcn_global_load_lds(
      (const __attribute__((address_space(1))) void*)g,
      (__attribute__((address_space(3))) void*)lds,
      16, 0, 0);
}

// ---------- converts (fused) ----------
__global__ __launch_bounds__(256) void k_cvt2(const float* __restrict__ x,
                                              const float* __restrict__ y,
                                              u16* __restrict__ xb, u16* __restrict__ yb) {
  const float* src = blockIdx.z ? y : x;
  u16* dst = blockIdx.z ? yb : xb;
  const int n8 = BT * Dd / 8;
  int i = blockIdx.x * blockDim.x + threadIdx.x;
  int stride = gridDim.x * blockDim.x;
  for (; i < n8; i += stride) {
    const float4* p = reinterpret_cast<const float4*>(src) + (size_t)i * 2;
    float4 a = p[0], b = p[1];
    u16x8 o;
    o[0] = f2bf(a.x); o[1] = f2bf(a.y); o[2] = f2bf(a.z); o[3] = f2bf(a.w);
    o[4] = f2bf(b.x); o[5] = f2bf(b.y); o[6] = f2bf(b.z); o[7] = f2bf(b.w);
    reinterpret_cast<u16x8*>(dst)[i] = o;
  }
}

__global__ __launch_bounds__(256) void k_cvt5(const float* __restrict__ a0,
                                              const float* __restrict__ a1,
                                              const float* __restrict__ a2,
                                              const float* __restrict__ a3,
                                              const float* __restrict__ a4,
                                              u16* __restrict__ Wb) {
  int z = blockIdx.z;
  const float* src = (z == 0) ? a0 : (z == 1) ? a1 : (z == 2) ? a2 : (z == 3) ? a3 : a4;
  u16* dst = Wb + (size_t)z * (Dd * Dd);
  int i = blockIdx.x * blockDim.x + threadIdx.x;   // 512*256 = 131072 = (Dd*Dd)/8 exactly
  const float4* p = reinterpret_cast<const float4*>(src) + (size_t)i * 2;
  float4 a = p[0], b = p[1];
  u16x8 o;
  o[0] = f2bf(a.x); o[1] = f2bf(a.y); o[2] = f2bf(a.z); o[3] = f2bf(a.w);
  o[4] = f2bf(b.x); o[5] = f2bf(b.y); o[6] = f2bf(b.z); o[7] = f2bf(b.w);
  reinterpret_cast<u16x8*>(dst)[i] = o;
}

// ---------- fused projection GEMM: C = A[8192,1024] @ Wqkv[3072,1024]^T ----------
// z: 0 -> A=x, 1 -> A=y. Epilogue routes to Qb/Kb (attn row layout) or Vtg (transposed).
__global__ __launch_bounds__(256) void k_gemm_proj(const u16* __restrict__ xb,
                                                   const u16* __restrict__ yb,
                                                   const u16* __restrict__ W,
                                                   u16* __restrict__ Qb,
                                                   u16* __restrict__ Kb,
                                                   u16* __restrict__ Vtg) {
  __shared__ alignas(16) u16 As[128 * 32];
  __shared__ alignas(16) u16 Bs[128 * 32];
  const int tid = threadIdx.x;
  const int l = tid & 63, w = tid >> 6;
  const int isY = blockIdx.z;
  const u16* A = isY ? yb : xb;
  const int m0 = blockIdx.y * 128;
  const int n0 = blockIdx.x * 128;
  const int wr = (w >> 1) * 64, wc = (w & 1) * 64;

  f32x4 acc[4][4] = {};

  for (int kt = 0; kt < 32; ++kt) {
    const int kbase = kt * 32;
#pragma unroll
    for (int rep = 0; rep < 2; ++rep) {
      int chunk = rep * 4 + w;
      int idx = chunk * 64 + l;
      int row = idx >> 2;
      int p = idx & 3;
      int g = p ^ ((row >> 1) & 3);
      gload_lds16(A + (size_t)(m0 + row) * 1024 + kbase + g * 8, &As[chunk * 512]);
      gload_lds16(W + (size_t)(n0 + row) * 1024 + kbase + g * 8, &Bs[chunk * 512]);
    }
    __syncthreads();

    bf16x8 af[4], bfr[4];
#pragma unroll
    for (int mi = 0; mi < 4; ++mi) {
      int row = wr + mi * 16 + (l & 15);
      int p = (l >> 4) ^ ((row >> 1) & 3);
      af[mi] = *reinterpret_cast<const bf16x8*>(&As[row * 32 + p * 8]);
    }
#pragma unroll
    for (int ni = 0; ni < 4; ++ni) {
      int row = wc + ni * 16 + (l & 15);
      int p = (l >> 4) ^ ((row >> 1) & 3);
      bfr[ni] = *reinterpret_cast<const bf16x8*>(&Bs[row * 32 + p * 8]);
    }
#pragma unroll
    for (int mi = 0; mi < 4; ++mi)
#pragma unroll
      for (int ni = 0; ni < 4; ++ni)
        acc[mi][ni] = __builtin_amdgcn_mfma_f32_16x16x32_bf16(af[mi], bfr[ni], acc[mi][ni], 0, 0, 0);
    __syncthreads();
  }

#pragma unroll
  for (int mi = 0; mi < 4; ++mi)
#pragma unroll
    for (int ni = 0; ni < 4; ++ni) {
      int rb = m0 + wr + mi * 16 + (l >> 4) * 4;   // base row (t), +j stays in same 1024-block
      int col = n0 + wc + ni * 16 + (l & 15);
      int proj = col >> 10;                         // 0=Q 1=K 2=V
      int slot = ((proj == 0) ? 1 : 0) ^ isY;
      int bh = ((rb >> 10) << 4) + ((col >> 6) & 15);
      int t0 = rb & 1023;
      int d0 = col & 63;
      if (proj == 2) {
        u16x4v pk;
#pragma unroll
        for (int j = 0; j < 4; ++j) pk[j] = f2bf(acc[mi][ni][j]);
        *reinterpret_cast<u16x4v*>(Vtg + (size_t)bh * 131072 + (size_t)(slot * 64 + d0) * 1024 + t0) = pk;
      } else {
        float sc = (proj == 0) ? 0.0625f : 1.0f;   // fold 0.5/sqrt(64) into Q
        u16* dst = (proj ? Kb : Qb) + (size_t)bh * 131072 + (size_t)t0 * 128 + slot * 64 + d0;
#pragma unroll
        for (int j = 0; j < 4; ++j) dst[(size_t)j * 128] = f2bf(acc[mi][ni][j] * sc);
      }
    }
}

// ---------- output GEMM: out[z] = merge(O slot z) @ Wo[z]^T + b[z] ----------
__global__ __launch_bounds__(256) void k_gemm_out(const u16* __restrict__ Ob,
                                                  const u16* __restrict__ W2,
                                                  const float* __restrict__ bx,
                                                  const float* __restrict__ by,
                                                  float* __restrict__ out) {
  __shared__ alignas(16) u16 As[128 * 32];
  __shared__ alignas(16) u16 Bs[128 * 32];
  const int tid = threadIdx.x;
  const int l = tid & 63, w = tid >> 6;
  const int z = blockIdx.z;
  const u16* A = Ob + z * 64;
  const u16* W = W2 + (size_t)z * (Dd * Dd);
  const float* bias = z ? by : bx;
  float* dst = out + (size_t)z * BT * Dd;
  const int m0 = blockIdx.y * 128;
  const int n0 = blockIdx.x * 128;
  const int wr = (w >> 1) * 64, wc = (w & 1) * 64;

  f32x4 acc[4][4] = {};

  for (int kt = 0; kt < 32; ++kt) {
    const int kbase = kt * 32;
#pragma unroll
    for (int rep = 0; rep < 2; ++rep) {
      int chunk = rep * 4 + w;
      int idx = chunk * 64 + l;
      int row = idx >> 2;
      int p = idx & 3;
      int g = p ^ ((row >> 1) & 3);
      int m = m0 + row;
      int k = kbase + g * 8;
      gload_lds16(A + ((size_t)((m >> 10) * 16 + (k >> 6)) * 1024 + (m & 1023)) * 128 + (k & 63),
                  &As[chunk * 512]);
      gload_lds16(W + (size_t)(n0 + row) * 1024 + k, &Bs[chunk * 512]);
    }
    __syncthreads();

    bf16x8 af[4], bfr[4];
#pragma unroll
    for (int mi = 0; mi < 4; ++mi) {
      int row = wr + mi * 16 + (l & 15);
      int p = (l >> 4) ^ ((row >> 1) & 3);
      af[mi] = *reinterpret_cast<const bf16x8*>(&As[row * 32 + p * 8]);
    }
#pragma unroll
    for (int ni = 0; ni < 4; ++ni) {
      int row = wc + ni * 16 + (l & 15);
      int p = (l >> 4) ^ ((row >> 1) & 3);
      bfr[ni] = *reinterpret_cast<const bf16x8*>(&Bs[row * 32 + p * 8]);
    }
#pragma unroll
    for (int mi = 0; mi < 4; ++mi)
#pragma unroll
      for (int ni = 0; ni < 4; ++ni)
        acc[mi][ni] = __builtin_amdgcn_mfma_f32_16x16x32_bf16(af[mi], bfr[ni], acc[mi][ni], 0, 0, 0);
    __syncthreads();
  }

#pragma unroll
  for (int mi = 0; mi < 4; ++mi)
#pragma unroll
    for (int ni = 0; ni < 4; ++ni)
#pragma unroll
      for (int j = 0; j < 4; ++j) {
        int row = m0 + wr + mi * 16 + (l >> 4) * 4 + j;
        int col = n0 + wc + ni * 16 + (l & 15);
        dst[(size_t)row * 1024 + col] = acc[mi][ni][j] + bias[col];
      }
}

// ---------- flash attention, concat head-dim 128, swapped QK^T, KVB=64 ----------
// grid: 2048 1-D blocks. XCD-aware decode: all 16 q-blocks of a bh on one XCD.
__global__ __launch_bounds__(256) void k_attn(const u16* __restrict__ Q,
                                              const u16* __restrict__ K,
                                              const u16* __restrict__ Vt,
                                              u16* __restrict__ O) {
  __shared__ alignas(16) u16 Ks[64 * 128];   // [kv][d], swz granule G^(row&7)
  __shared__ alignas(16) u16 Vs[128 * 64];   // [d][kv], swz granule g^(d&7)
  const int tid = threadIdx.x;
  const int l = tid & 63, w = tid >> 6;
  const int bid = blockIdx.x;
  const int xcd = bid & 7, li = bid >> 3;
  const int bh = xcd + 8 * (li >> 4);
  const int qx = li & 15;
  const int q0 = qx * 64 + w * 16;
  const size_t base = (size_t)bh * 131072;

  bf16x8 qf[4];
#pragma unroll
  for (int dc = 0; dc < 4; ++dc)
    qf[dc] = *reinterpret_cast<const bf16x8*>(
        Q + base + (size_t)(q0 + (l & 15)) * 128 + dc * 32 + (l >> 4) * 8);

  float m_run = -3e38f, l_run = 0.f;
  f32x4 Oa[8] = {};

  for (int kv0 = 0; kv0 < 1024; kv0 += 64) {
    // stage K [64][128] and V^T [128][64] via global_load_lds (pre-swizzled source)
#pragma unroll
    for (int rep = 0; rep < 4; ++rep) {
      int chunk = rep * 4 + w;
      int idx = chunk * 64 + l;
      {
        int row = idx >> 4, P = idx & 15, G = P ^ (row & 7);
        gload_lds16(K + base + (size_t)(kv0 + row) * 128 + G * 8, &Ks[chunk * 512]);
      }
      {
        int d = idx >> 3, p = idx & 7, g = p ^ (d & 7);
        gload_lds16(Vt + base + (size_t)d * 1024 + kv0 + g * 8, &Vs[chunk * 512]);
      }
    }
    __syncthreads();

    // swapped QK^T: S^T[kv][q] = mfma(A=K, B=Q); lane holds kv = t*16+4*(l>>4)+j, q = l&15
    f32x4 S[4];
#pragma unroll
    for (int t = 0; t < 4; ++t) {
      f32x4 s = {};
      int row = t * 16 + (l & 15);
#pragma unroll
      for (int dc = 0; dc < 4; ++dc) {
        int P = (dc * 4 + (l >> 4)) ^ (row & 7);
        bf16x8 kb = *reinterpret_cast<const bf16x8*>(&Ks[row * 128 + P * 8]);
        s = __builtin_amdgcn_mfma_f32_16x16x32_bf16(kb, qf[dc], s, 0, 0, 0);
      }
      S[t] = s;
    }

    // online softmax per q (= l&15 column): in-lane 16 + cross-group shfl(16,32)
    float mx = S[0][0];
#pragma unroll
    for (int t = 0; t < 4; ++t)
#pragma unroll
      for (int j = 0; j < 4; ++j) mx = fmaxf(mx, S[t][j]);
    mx = fmaxf(mx, __shfl_xor(mx, 16));
    mx = fmaxf(mx, __shfl_xor(mx, 32));
    float mn = fmaxf(m_run, mx);
    float alpha = __expf(m_run - mn);
    m_run = mn;
    float p[4][4];
    float rs = 0.f;
#pragma unroll
    for (int t = 0; t < 4; ++t)
#pragma unroll
      for (int j = 0; j < 4; ++j) {
        p[t][j] = __expf(S[t][j] - mn);
        rs += p[t][j];
      }
    rs += __shfl_xor(rs, 16);
    rs += __shfl_xor(rs, 32);
    l_run = alpha * l_run + rs;

    // pack P to bf16 pairs (per tile: 2 u32 = 4 values)
    u32 u[4][2];
#pragma unroll
    for (int t = 0; t < 4; ++t) {
      u[t][0] = pack2(p[t][0], p[t][1]);
      u[t][1] = pack2(p[t][2], p[t][3]);
    }

    // rescale Oa by alpha of each output row q=(l>>4)*4+j
    {
      f32x4 av;
#pragma unroll
      for (int j = 0; j < 4; ++j) av[j] = __shfl(alpha, (l >> 4) * 4 + j);
#pragma unroll
      for (int n = 0; n < 8; ++n) Oa[n] *= av;
    }

    // assemble P A-fragments in-register and do PV
    const bool hi = (l >= 32);
    const int srcA = (l & 15) + ((l >> 4) & 1) * 32;   // lane holding gA = 2*((l>>4)&1)
#pragma unroll
    for (int c = 0; c < 2; ++c) {
      u32 r0a = __shfl(u[2 * c][0], srcA),      r0b = __shfl(u[2 * c + 1][0], srcA);
      u32 r1a = __shfl(u[2 * c][1], srcA),      r1b = __shfl(u[2 * c + 1][1], srcA);
      u32 r2a = __shfl(u[2 * c][0], srcA + 16), r2b = __shfl(u[2 * c + 1][0], srcA + 16);
      u32 r3a = __shfl(u[2 * c][1], srcA + 16), r3b = __shfl(u[2 * c + 1][1], srcA + 16);
      union { u32 wd[4]; bf16x8 v; } pu;
      pu.wd[0] = hi ? r0b : r0a;
      pu.wd[1] = hi ? r1b : r1a;
      pu.wd[2] = hi ? r2b : r2a;
      pu.wd[3] = hi ? r3b : r3a;
      bf16x8 pa = pu.v;
#pragma unroll
      for (int n = 0; n < 8; ++n) {
        int d = n * 16 + (l & 15);
        int pp = (c * 4 + (l >> 4)) ^ (d & 7);
        bf16x8 vb = *reinterpret_cast<const bf16x8*>(&Vs[d * 64 + pp * 8]);
        Oa[n] = __builtin_amdgcn_mfma_f32_16x16x32_bf16(pa, vb, Oa[n], 0, 0, 0);
      }
    }
    __syncthreads();
  }

  // epilogue: normalize by l_run of each output row, store
  float inv = 1.0f / l_run;
  f32x4 iv;
#pragma unroll
  for (int j = 0; j < 4; ++j) iv[j] = __shfl(inv, (l >> 4) * 4 + j);
#pragma unroll
  for (int n = 0; n < 8; ++n)
#pragma unroll
    for (int j = 0; j < 4; ++j)
      O[base + (size_t)(q0 + (l >> 4) * 4 + j) * 128 + n * 16 + (l & 15)] = f2bf(Oa[n][j] * iv[j]);
}

// ---------- launch ----------
extern "C" void kernel_launch(void* const* d_in, const int* in_sizes, int n_in,
                              void* d_out, int out_size, void* d_ws, size_t ws_size,
                              hipStream_t stream) {
  const float* x   = (const float*)d_in[0];
  const float* y   = (const float*)d_in[1];
  const float* Wq  = (const float*)d_in[2];
  const float* Wk  = (const float*)d_in[3];
  const float* Wv  = (const float*)d_in[4];
  const float* Wox = (const float*)d_in[5];
  const float* box = (const float*)d_in[6];
  const float* Woy = (const float*)d_in[7];
  const float* boy = (const float*)d_in[8];

  u16* ws = (u16*)d_ws;
  size_t off = 0;
  u16* xb  = ws + off; off += (size_t)BT * Dd;
  u16* yb  = ws + off; off += (size_t)BT * Dd;
  u16* Wqb = ws + off; off += (size_t)Dd * Dd;   // Wq,Wk,Wv contiguous (concat N=3072)
  u16* Wkb = ws + off; off += (size_t)Dd * Dd;
  u16* Wvb = ws + off; off += (size_t)Dd * Dd;
  u16* Woxb = ws + off; off += (size_t)Dd * Dd;  // Wox,Woy contiguous (z-select)
  u16* Woyb = ws + off; off += (size_t)Dd * Dd;
  (void)Wkb; (void)Wvb; (void)Woyb;
  const size_t attn_elems = (size_t)Bb * Hh * Tt * 128;  // 16.78M
  u16* Qb = ws + off; off += attn_elems;
  u16* Kb = ws + off; off += attn_elems;
  u16* Vb = ws + off; off += attn_elems;   // transposed layout [bh][128][1024]
  u16* Ob = ws + off; off += attn_elems;

  k_cvt2<<<dim3(1024, 1, 2), dim3(256), 0, stream>>>(x, y, xb, yb);
  k_cvt5<<<dim3(512, 1, 5), dim3(256), 0, stream>>>(Wq, Wk, Wv, Wox, Woy, Wqb);

  k_gemm_proj<<<dim3(24, 64, 2), dim3(256), 0, stream>>>(xb, yb, Wqb, Qb, Kb, Vb);

  k_attn<<<dim3(2048), dim3(256), 0, stream>>>(Qb, Kb, Vb, Ob);

  k_gemm_out<<<dim3(8, 64, 2), dim3(256), 0, stream>>>(Ob, Woxb, box, boy, (float*)d_out);
}

// Round 3
// 302.532 us; speedup vs baseline: 1.5934x; 1.1855x over previous
//
#include <hip/hip_runtime.h>
#include <stdint.h>

#define DEV __device__ __forceinline__

typedef __bf16 bf16x8 __attribute__((ext_vector_type(8)));
typedef float f32x4 __attribute__((ext_vector_type(4)));
typedef unsigned short u16;
typedef u16 u16x4v __attribute__((ext_vector_type(4)));
typedef u16 u16x8 __attribute__((ext_vector_type(8)));
typedef uint32_t u32;

static constexpr int Bb = 8, Tt = 1024, Dd = 1024, Hh = 16;
static constexpr int BT = Bb * Tt;      // 8192

// ---------- helpers ----------
DEV u16 f2bf(float f) {
  u32 u = __float_as_uint(f);
  u32 r = (u + 0x7FFFu + ((u >> 16) & 1u)) >> 16;
  return (u16)r;
}
DEV u32 pack2(float a, float b) {
  return (u32)f2bf(a) | ((u32)f2bf(b) << 16);
}
DEV void gload_lds16(const void* g, void* lds) {
  __builtin_amdgcn_global_load_lds(
      (const __attribute__((address_space(1))) void*)g,
      (__attribute__((address_space(3))) void*)lds,
      16, 0, 0);
}

// ---------- converts ----------
__global__ __launch_bounds__(256) void k_cvt2(const float* __restrict__ x,
                                              const float* __restrict__ y,
                                              u16* __restrict__ xb, u16* __restrict__ yb) {
  const float* src = blockIdx.z ? y : x;
  u16* dst = blockIdx.z ? yb : xb;
  const int n8 = BT * Dd / 8;
  int i = blockIdx.x * blockDim.x + threadIdx.x;
  int stride = gridDim.x * blockDim.x;
  for (; i < n8; i += stride) {
    const float4* p = reinterpret_cast<const float4*>(src) + (size_t)i * 2;
    float4 a = p[0], b = p[1];
    u16x8 o;
    o[0] = f2bf(a.x); o[1] = f2bf(a.y); o[2] = f2bf(a.z); o[3] = f2bf(a.w);
    o[4] = f2bf(b.x); o[5] = f2bf(b.y); o[6] = f2bf(b.z); o[7] = f2bf(b.w);
    reinterpret_cast<u16x8*>(dst)[i] = o;
  }
}

__global__ __launch_bounds__(256) void k_cvt5(const float* __restrict__ a0,
                                              const float* __restrict__ a1,
                                              const float* __restrict__ a2,
                                              const float* __restrict__ a3,
                                              const float* __restrict__ a4,
                                              u16* __restrict__ Wb) {
  int z = blockIdx.z;
  const float* src = (z == 0) ? a0 : (z == 1) ? a1 : (z == 2) ? a2 : (z == 3) ? a3 : a4;
  u16* dst = Wb + (size_t)z * (Dd * Dd);
  int i = blockIdx.x * blockDim.x + threadIdx.x;   // 512*256 = (Dd*Dd)/8 exactly
  const float4* p = reinterpret_cast<const float4*>(src) + (size_t)i * 2;
  float4 a = p[0], b = p[1];
  u16x8 o;
  o[0] = f2bf(a.x); o[1] = f2bf(a.y); o[2] = f2bf(a.z); o[3] = f2bf(a.w);
  o[4] = f2bf(b.x); o[5] = f2bf(b.y); o[6] = f2bf(b.z); o[7] = f2bf(b.w);
  reinterpret_cast<u16x8*>(dst)[i] = o;
}

// ---------- 256x256-tile 8-wave 4-phase dbuf GEMM ----------
// MODE 0 (proj): A = (tz? yb : xb) dense [8192,1024]; W = Wqkv [3072,1024];
//                epilogue routes Q/K (row layout, Q scaled 0.0625) and V (transposed).
// MODE 1 (out):  A = Ob gather (+tz*64 slot); W = Wo[tz]; epilogue f32 + bias.
template <int MODE, int GX, int GY>
__global__ __launch_bounds__(512, 2) void k_gemm256(
    const u16* __restrict__ xb, const u16* __restrict__ yb,
    const u16* __restrict__ W0,
    u16* __restrict__ Qb, u16* __restrict__ Kb, u16* __restrict__ Vtg,
    const float* __restrict__ bx, const float* __restrict__ by,
    float* __restrict__ out) {
  __shared__ alignas(16) u16 As[2][256 * 64];
  __shared__ alignas(16) u16 Bs[2][256 * 64];
  const int tid = threadIdx.x;
  const int l = tid & 63, wid = tid >> 6;
  const int wr = wid >> 2, wc = wid & 3;

  constexpr int NWG = GX * GY * 2;
  const int d0b = blockIdx.x;
  const int wk = (d0b & 7) * (NWG / 8) + (d0b >> 3);
  const int tz = wk / (GX * GY);
  const int rr = wk % (GX * GY);
  const int ty = rr / GX, tx = rr % GX;
  const int m0 = ty * 256, n0 = tx * 256;

  const u16* Ag;
  const u16* Wg;
  if constexpr (MODE == 0) {
    Ag = tz ? yb : xb;
    Wg = W0;
  } else {
    Ag = xb + tz * 64;                       // xb carries Ob
    Wg = W0 + (size_t)tz * (Dd * Dd);
  }

  auto stageA = [&](int buf, int kt, int half) {
#pragma unroll
    for (int i = 0; i < 2; ++i) {
      int idx = i * 512 + tid;
      int row = idx >> 3, P = idx & 7, G = P ^ (row & 7);
      const u16* src;
      if constexpr (MODE == 0) {
        src = Ag + (size_t)(m0 + half * 128 + row) * 1024 + kt * 64 + G * 8;
      } else {
        int m = m0 + half * 128 + row;
        src = Ag + ((size_t)((m >> 10) * 16 + kt) * 1024 + (m & 1023)) * 128 + G * 8;
      }
      gload_lds16(src, &As[buf][half * 8192 + idx * 8]);
    }
  };
  auto stageB = [&](int buf, int kt, int half) {
#pragma unroll
    for (int i = 0; i < 2; ++i) {
      int idx = i * 512 + tid;
      int row = idx >> 3, P = idx & 7, G = P ^ (row & 7);
      gload_lds16(Wg + (size_t)(n0 + half * 128 + row) * 1024 + kt * 64 + G * 8,
                  &Bs[buf][half * 8192 + idx * 8]);
    }
  };
  auto ldA = [&](int b, int m, int kk) -> bf16x8 {
    int row = wr * 128 + m * 16 + (l & 15);
    int P = (kk * 4 + (l >> 4)) ^ (row & 7);
    return *reinterpret_cast<const bf16x8*>(&As[b][row * 64 + P * 8]);
  };
  auto ldB = [&](int b, int n, int kk) -> bf16x8 {
    int row = wc * 64 + n * 16 + (l & 15);
    int P = (kk * 4 + (l >> 4)) ^ (row & 7);
    return *reinterpret_cast<const bf16x8*>(&Bs[b][row * 64 + P * 8]);
  };

  f32x4 acc[8][4] = {};

  // prologue: stage K-tile 0 fully, drain, barrier
  stageA(0, 0, 0); stageB(0, 0, 0); stageA(0, 0, 1); stageB(0, 0, 1);
  asm volatile("s_waitcnt vmcnt(0)" ::: "memory");
  __builtin_amdgcn_s_barrier();

  for (int kt = 0; kt < 16; ++kt) {
    const int b = kt & 1, nb = b ^ 1;
    const bool pf = (kt < 15);
    bf16x8 bfr[4][2], afr[2][2];

#define QUAD(p)                                                                     \
  do {                                                                              \
    __builtin_amdgcn_s_barrier();                                                   \
    asm volatile("s_waitcnt lgkmcnt(0)" ::: "memory");                              \
    __builtin_amdgcn_sched_barrier(0);                                              \
    __builtin_amdgcn_s_setprio(1);                                                  \
    _Pragma("unroll") for (int mm = 0; mm < 2; ++mm)                                \
        _Pragma("unroll") for (int n = 0; n < 4; ++n)                               \
            _Pragma("unroll") for (int kk = 0; kk < 2; ++kk)                        \
                acc[2 * (p) + mm][n] = __builtin_amdgcn_mfma_f32_16x16x32_bf16(     \
                    afr[mm][kk], bfr[n][kk], acc[2 * (p) + mm][n], 0, 0, 0);        \
    __builtin_amdgcn_s_setprio(0);                                                  \
  } while (0)

    // ---- phase 0: all B + A quad 0; stage half0 of next ----
#pragma unroll
    for (int n = 0; n < 4; ++n) { bfr[n][0] = ldB(b, n, 0); bfr[n][1] = ldB(b, n, 1); }
    afr[0][0] = ldA(b, 0, 0); afr[0][1] = ldA(b, 0, 1);
    afr[1][0] = ldA(b, 1, 0); afr[1][1] = ldA(b, 1, 1);
    if (pf) { stageA(nb, kt + 1, 0); stageB(nb, kt + 1, 0); }
    QUAD(0);
    __builtin_amdgcn_s_barrier();

    // ---- phase 1: A quad 1; stage half1 of next ----
    afr[0][0] = ldA(b, 2, 0); afr[0][1] = ldA(b, 2, 1);
    afr[1][0] = ldA(b, 3, 0); afr[1][1] = ldA(b, 3, 1);
    if (pf) { stageA(nb, kt + 1, 1); stageB(nb, kt + 1, 1); }
    QUAD(1);
    __builtin_amdgcn_s_barrier();

    // ---- phase 2: A quad 2 ----
    afr[0][0] = ldA(b, 4, 0); afr[0][1] = ldA(b, 4, 1);
    afr[1][0] = ldA(b, 5, 0); afr[1][1] = ldA(b, 5, 1);
    QUAD(2);
    __builtin_amdgcn_s_barrier();

    // ---- phase 3: A quad 3; K-tile boundary drain ----
    afr[0][0] = ldA(b, 6, 0); afr[0][1] = ldA(b, 6, 1);
    afr[1][0] = ldA(b, 7, 0); afr[1][1] = ldA(b, 7, 1);
    QUAD(3);
    asm volatile("s_waitcnt vmcnt(0)" ::: "memory");
    __builtin_amdgcn_s_barrier();
#undef QUAD
  }

  // ---- epilogue ----
#pragma unroll
  for (int m = 0; m < 8; ++m)
#pragma unroll
    for (int n = 0; n < 4; ++n) {
      int rb = m0 + wr * 128 + m * 16 + (l >> 4) * 4;
      int col = n0 + wc * 64 + n * 16 + (l & 15);
      if constexpr (MODE == 0) {
        int proj = col >> 10;                     // 0=Q 1=K 2=V
        int slot = ((proj == 0) ? 1 : 0) ^ tz;
        int bh = ((rb >> 10) << 4) + ((col >> 6) & 15);
        int t0 = rb & 1023;
        int dc = col & 63;
        if (proj == 2) {
          u16x4v pk;
#pragma unroll
          for (int j = 0; j < 4; ++j) pk[j] = f2bf(acc[m][n][j]);
          *reinterpret_cast<u16x4v*>(Vtg + (size_t)bh * 131072 +
                                     (size_t)(slot * 64 + dc) * 1024 + t0) = pk;
        } else {
          float sc = (proj == 0) ? 0.0625f : 1.0f;
          u16* dstp = (proj ? Kb : Qb) + (size_t)bh * 131072 + (size_t)t0 * 128 + slot * 64 + dc;
#pragma unroll
          for (int j = 0; j < 4; ++j) dstp[(size_t)j * 128] = f2bf(acc[m][n][j] * sc);
        }
      } else {
        const float* bias = tz ? by : bx;
        float* dstp = out + (size_t)tz * BT * Dd;
        float bv = bias[col];
#pragma unroll
        for (int j = 0; j < 4; ++j)
          dstp[(size_t)(rb + j) * 1024 + col] = acc[m][n][j] + bv;
      }
    }
}

// ---------- flash attention, concat head-dim 128, swapped QK^T, KVB=64 ----------
__global__ __launch_bounds__(256) void k_attn(const u16* __restrict__ Q,
                                              const u16* __restrict__ K,
                                              const u16* __restrict__ Vt,
                                              u16* __restrict__ O) {
  __shared__ alignas(16) u16 Ks[64 * 128];   // [kv][d], swz granule G^(row&7)
  __shared__ alignas(16) u16 Vs[128 * 64];   // [d][kv], swz granule g^(d&7)
  const int tid = threadIdx.x;
  const int l = tid & 63, w = tid >> 6;
  const int bid = blockIdx.x;
  const int xcd = bid & 7, li = bid >> 3;
  const int bh = xcd + 8 * (li >> 4);
  const int qx = li & 15;
  const int q0 = qx * 64 + w * 16;
  const size_t base = (size_t)bh * 131072;

  bf16x8 qf[4];
#pragma unroll
  for (int dc = 0; dc < 4; ++dc)
    qf[dc] = *reinterpret_cast<const bf16x8*>(
        Q + base + (size_t)(q0 + (l & 15)) * 128 + dc * 32 + (l >> 4) * 8);

  float m_run = -3e38f, l_run = 0.f;
  f32x4 Oa[8] = {};

  for (int kv0 = 0; kv0 < 1024; kv0 += 64) {
#pragma unroll
    for (int rep = 0; rep < 4; ++rep) {
      int chunk = rep * 4 + w;
      int idx = chunk * 64 + l;
      {
        int row = idx >> 4, P = idx & 15, G = P ^ (row & 7);
        gload_lds16(K + base + (size_t)(kv0 + row) * 128 + G * 8, &Ks[chunk * 512]);
      }
      {
        int d = idx >> 3, p = idx & 7, g = p ^ (d & 7);
        gload_lds16(Vt + base + (size_t)d * 1024 + kv0 + g * 8, &Vs[chunk * 512]);
      }
    }
    __syncthreads();

    // swapped QK^T: S^T[kv][q]
    f32x4 S[4];
    __builtin_amdgcn_s_setprio(1);
#pragma unroll
    for (int t = 0; t < 4; ++t) {
      f32x4 s = {};
      int row = t * 16 + (l & 15);
#pragma unroll
      for (int dc = 0; dc < 4; ++dc) {
        int P = (dc * 4 + (l >> 4)) ^ (row & 7);
        bf16x8 kb = *reinterpret_cast<const bf16x8*>(&Ks[row * 128 + P * 8]);
        s = __builtin_amdgcn_mfma_f32_16x16x32_bf16(kb, qf[dc], s, 0, 0, 0);
      }
      S[t] = s;
    }
    __builtin_amdgcn_s_setprio(0);

    float mx = S[0][0];
#pragma unroll
    for (int t = 0; t < 4; ++t)
#pragma unroll
      for (int j = 0; j < 4; ++j) mx = fmaxf(mx, S[t][j]);
    mx = fmaxf(mx, __shfl_xor(mx, 16));
    mx = fmaxf(mx, __shfl_xor(mx, 32));
    float mn = fmaxf(m_run, mx);
    float alpha = __expf(m_run - mn);
    m_run = mn;
    float p[4][4];
    float rs = 0.f;
#pragma unroll
    for (int t = 0; t < 4; ++t)
#pragma unroll
      for (int j = 0; j < 4; ++j) {
        p[t][j] = __expf(S[t][j] - mn);
        rs += p[t][j];
      }
    rs += __shfl_xor(rs, 16);
    rs += __shfl_xor(rs, 32);
    l_run = alpha * l_run + rs;

    u32 u[4][2];
#pragma unroll
    for (int t = 0; t < 4; ++t) {
      u[t][0] = pack2(p[t][0], p[t][1]);
      u[t][1] = pack2(p[t][2], p[t][3]);
    }

    {
      f32x4 av;
#pragma unroll
      for (int j = 0; j < 4; ++j) av[j] = __shfl(alpha, (l >> 4) * 4 + j);
#pragma unroll
      for (int n = 0; n < 8; ++n) Oa[n] *= av;
    }

    const bool hi = (l >= 32);
    const int srcA = (l & 15) + ((l >> 4) & 1) * 32;
#pragma unroll
    for (int c = 0; c < 2; ++c) {
      u32 r0a = __shfl(u[2 * c][0], srcA),      r0b = __shfl(u[2 * c + 1][0], srcA);
      u32 r1a = __shfl(u[2 * c][1], srcA),      r1b = __shfl(u[2 * c + 1][1], srcA);
      u32 r2a = __shfl(u[2 * c][0], srcA + 16), r2b = __shfl(u[2 * c + 1][0], srcA + 16);
      u32 r3a = __shfl(u[2 * c][1], srcA + 16), r3b = __shfl(u[2 * c + 1][1], srcA + 16);
      union { u32 wd[4]; bf16x8 v; } pu;
      pu.wd[0] = hi ? r0b : r0a;
      pu.wd[1] = hi ? r1b : r1a;
      pu.wd[2] = hi ? r2b : r2a;
      pu.wd[3] = hi ? r3b : r3a;
      bf16x8 pa = pu.v;
      __builtin_amdgcn_s_setprio(1);
#pragma unroll
      for (int n = 0; n < 8; ++n) {
        int d = n * 16 + (l & 15);
        int pp = (c * 4 + (l >> 4)) ^ (d & 7);
        bf16x8 vb = *reinterpret_cast<const bf16x8*>(&Vs[d * 64 + pp * 8]);
        Oa[n] = __builtin_amdgcn_mfma_f32_16x16x32_bf16(pa, vb, Oa[n], 0, 0, 0);
      }
      __builtin_amdgcn_s_setprio(0);
    }
    __syncthreads();
  }

  float inv = 1.0f / l_run;
  f32x4 iv;
#pragma unroll
  for (int j = 0; j < 4; ++j) iv[j] = __shfl(inv, (l >> 4) * 4 + j);
#pragma unroll
  for (int n = 0; n < 8; ++n)
#pragma unroll
    for (int j = 0; j < 4; ++j)
      O[base + (size_t)(q0 + (l >> 4) * 4 + j) * 128 + n * 16 + (l & 15)] = f2bf(Oa[n][j] * iv[j]);
}

// ---------- launch ----------
extern "C" void kernel_launch(void* const* d_in, const int* in_sizes, int n_in,
                              void* d_out, int out_size, void* d_ws, size_t ws_size,
                              hipStream_t stream) {
  const float* x   = (const float*)d_in[0];
  const float* y   = (const float*)d_in[1];
  const float* Wq  = (const float*)d_in[2];
  const float* Wk  = (const float*)d_in[3];
  const float* Wv  = (const float*)d_in[4];
  const float* Wox = (const float*)d_in[5];
  const float* box = (const float*)d_in[6];
  const float* Woy = (const float*)d_in[7];
  const float* boy = (const float*)d_in[8];

  u16* ws = (u16*)d_ws;
  size_t off = 0;
  u16* xb  = ws + off; off += (size_t)BT * Dd;
  u16* yb  = ws + off; off += (size_t)BT * Dd;
  u16* Wqb = ws + off; off += (size_t)Dd * Dd;   // Wq,Wk,Wv contiguous
  u16* Wkb = ws + off; off += (size_t)Dd * Dd;
  u16* Wvb = ws + off; off += (size_t)Dd * Dd;
  u16* Woxb = ws + off; off += (size_t)Dd * Dd;  // Wox,Woy contiguous
  u16* Woyb = ws + off; off += (size_t)Dd * Dd;
  (void)Wkb; (void)Wvb; (void)Woyb;
  const size_t attn_elems = (size_t)Bb * Hh * Tt * 128;
  u16* Qb = ws + off; off += attn_elems;
  u16* Kb = ws + off; off += attn_elems;
  u16* Vb = ws + off; off += attn_elems;   // transposed [bh][128][1024]
  u16* Ob = ws + off; off += attn_elems;

  k_cvt2<<<dim3(1024, 1, 2), dim3(256), 0, stream>>>(x, y, xb, yb);
  k_cvt5<<<dim3(512, 1, 5), dim3(256), 0, stream>>>(Wq, Wk, Wv, Wox, Woy, Wqb);

  k_gemm256<0, 12, 32><<<dim3(768), dim3(512), 0, stream>>>(
      xb, yb, Wqb, Qb, Kb, Vb, nullptr, nullptr, nullptr);

  k_attn<<<dim3(2048), dim3(256), 0, stream>>>(Qb, Kb, Vb, Ob);

  k_gemm256<1, 4, 32><<<dim3(256), dim3(512), 0, stream>>>(
      Ob, nullptr, Woxb, nullptr, nullptr, nullptr, box, boy, (float*)d_out);
}

// Round 4
// 292.750 us; speedup vs baseline: 1.6467x; 1.0334x over previous
//
#include <hip/hip_runtime.h>
#include <stdint.h>

#define DEV __device__ __forceinline__

typedef __bf16 bf16x8 __attribute__((ext_vector_type(8)));
typedef __bf16 bf16x4 __attribute__((ext_vector_type(4)));
typedef short s16x4 __attribute__((ext_vector_type(4)));
typedef float f32x4 __attribute__((ext_vector_type(4)));
typedef unsigned short u16;
typedef u16 u16x4v __attribute__((ext_vector_type(4)));
typedef u16 u16x8 __attribute__((ext_vector_type(8)));
typedef uint32_t u32;

static constexpr int Bb = 8, Tt = 1024, Dd = 1024, Hh = 16;
static constexpr int BT = Bb * Tt;      // 8192

// ---------- helpers ----------
DEV u16 f2bf(float f) {
  u32 u = __float_as_uint(f);
  u32 r = (u + 0x7FFFu + ((u >> 16) & 1u)) >> 16;
  return (u16)r;
}
DEV u32 cvtpk(float lo, float hi) {
  u32 r;
  asm("v_cvt_pk_bf16_f32 %0, %1, %2" : "=v"(r) : "v"(lo), "v"(hi));
  return r;
}
DEV void gload_lds16(const void* g, void* lds) {
  __builtin_amdgcn_global_load_lds(
      (const __attribute__((address_space(1))) void*)g,
      (__attribute__((address_space(3))) void*)lds,
      16, 0, 0);
}
DEV f32x4 MFMA16(bf16x4 a, bf16x4 b, f32x4 c) {
#if __has_builtin(__builtin_amdgcn_mfma_f32_16x16x16_bf16)
  return __builtin_amdgcn_mfma_f32_16x16x16_bf16(a, b, c, 0, 0, 0);
#elif __has_builtin(__builtin_amdgcn_mfma_f32_16x16x16bf16_1k)
  union { bf16x4 b; s16x4 s; } ua, ub;
  ua.b = a; ub.b = b;
  return __builtin_amdgcn_mfma_f32_16x16x16bf16_1k(ua.s, ub.s, c, 0, 0, 0);
#else
  asm("v_mfma_f32_16x16x16_bf16 %0, %1, %2, %0" : "+v"(c) : "v"(a), "v"(b));
  return c;
#endif
}

// ---------- converts ----------
__global__ __launch_bounds__(256) void k_cvt2(const float* __restrict__ x,
                                              const float* __restrict__ y,
                                              u16* __restrict__ xb, u16* __restrict__ yb) {
  const float* src = blockIdx.z ? y : x;
  u16* dst = blockIdx.z ? yb : xb;
  const int n8 = BT * Dd / 8;
  int i = blockIdx.x * blockDim.x + threadIdx.x;
  int stride = gridDim.x * blockDim.x;
  for (; i < n8; i += stride) {
    const float4* p = reinterpret_cast<const float4*>(src) + (size_t)i * 2;
    float4 a = p[0], b = p[1];
    u16x8 o;
    o[0] = f2bf(a.x); o[1] = f2bf(a.y); o[2] = f2bf(a.z); o[3] = f2bf(a.w);
    o[4] = f2bf(b.x); o[5] = f2bf(b.y); o[6] = f2bf(b.z); o[7] = f2bf(b.w);
    reinterpret_cast<u16x8*>(dst)[i] = o;
  }
}

__global__ __launch_bounds__(256) void k_cvt5(const float* __restrict__ a0,
                                              const float* __restrict__ a1,
                                              const float* __restrict__ a2,
                                              const float* __restrict__ a3,
                                              const float* __restrict__ a4,
                                              u16* __restrict__ Wb) {
  int z = blockIdx.z;
  const float* src = (z == 0) ? a0 : (z == 1) ? a1 : (z == 2) ? a2 : (z == 3) ? a3 : a4;
  u16* dst = Wb + (size_t)z * (Dd * Dd);
  int i = blockIdx.x * blockDim.x + threadIdx.x;
  const float4* p = reinterpret_cast<const float4*>(src) + (size_t)i * 2;
  float4 a = p[0], b = p[1];
  u16x8 o;
  o[0] = f2bf(a.x); o[1] = f2bf(a.y); o[2] = f2bf(a.z); o[3] = f2bf(a.w);
  o[4] = f2bf(b.x); o[5] = f2bf(b.y); o[6] = f2bf(b.z); o[7] = f2bf(b.w);
  reinterpret_cast<u16x8*>(dst)[i] = o;
}

// ---------- 256x256-tile 8-wave 4-phase dbuf GEMM ----------
template <int MODE, int GX, int GY>
__global__ __launch_bounds__(512, 2) void k_gemm256(
    const u16* __restrict__ xb, const u16* __restrict__ yb,
    const u16* __restrict__ W0,
    u16* __restrict__ Qb, u16* __restrict__ Kb, u16* __restrict__ Vtg,
    const float* __restrict__ bx, const float* __restrict__ by,
    float* __restrict__ out) {
  __shared__ alignas(16) u16 As[2][256 * 64];
  __shared__ alignas(16) u16 Bs[2][256 * 64];
  const int tid = threadIdx.x;
  const int l = tid & 63, wid = tid >> 6;
  const int wr = wid >> 2, wc = wid & 3;

  constexpr int NWG = GX * GY * 2;
  const int d0b = blockIdx.x;
  const int wk = (d0b & 7) * (NWG / 8) + (d0b >> 3);
  const int tz = wk / (GX * GY);
  const int rr = wk % (GX * GY);
  const int ty = rr / GX, tx = rr % GX;
  const int m0 = ty * 256, n0 = tx * 256;

  const u16* Ag;
  const u16* Wg;
  if constexpr (MODE == 0) {
    Ag = tz ? yb : xb;
    Wg = W0;
  } else {
    Ag = xb + tz * 64;                       // xb carries Ob
    Wg = W0 + (size_t)tz * (Dd * Dd);
  }

  auto stageA = [&](int buf, int kt, int half) {
#pragma unroll
    for (int i = 0; i < 2; ++i) {
      int idx = i * 512 + tid;
      int row = idx >> 3, P = idx & 7, G = P ^ (row & 7);
      const u16* src;
      if constexpr (MODE == 0) {
        src = Ag + (size_t)(m0 + half * 128 + row) * 1024 + kt * 64 + G * 8;
      } else {
        int m = m0 + half * 128 + row;
        src = Ag + ((size_t)((m >> 10) * 16 + kt) * 1024 + (m & 1023)) * 128 + G * 8;
      }
      gload_lds16(src, &As[buf][half * 8192 + idx * 8]);
    }
  };
  auto stageB = [&](int buf, int kt, int half) {
#pragma unroll
    for (int i = 0; i < 2; ++i) {
      int idx = i * 512 + tid;
      int row = idx >> 3, P = idx & 7, G = P ^ (row & 7);
      gload_lds16(Wg + (size_t)(n0 + half * 128 + row) * 1024 + kt * 64 + G * 8,
                  &Bs[buf][half * 8192 + idx * 8]);
    }
  };
  auto ldA = [&](int b, int m, int kk) -> bf16x8 {
    int row = wr * 128 + m * 16 + (l & 15);
    int P = (kk * 4 + (l >> 4)) ^ (row & 7);
    return *reinterpret_cast<const bf16x8*>(&As[b][row * 64 + P * 8]);
  };
  auto ldB = [&](int b, int n, int kk) -> bf16x8 {
    int row = wc * 64 + n * 16 + (l & 15);
    int P = (kk * 4 + (l >> 4)) ^ (row & 7);
    return *reinterpret_cast<const bf16x8*>(&Bs[b][row * 64 + P * 8]);
  };

  f32x4 acc[8][4] = {};

  stageA(0, 0, 0); stageB(0, 0, 0); stageA(0, 0, 1); stageB(0, 0, 1);
  asm volatile("s_waitcnt vmcnt(0)" ::: "memory");
  __builtin_amdgcn_s_barrier();

  for (int kt = 0; kt < 16; ++kt) {
    const int b = kt & 1, nb = b ^ 1;
    const bool pf = (kt < 15);
    bf16x8 bfr[4][2], afr[2][2];

#define QUAD(p)                                                                     \
  do {                                                                              \
    __builtin_amdgcn_s_barrier();                                                   \
    asm volatile("s_waitcnt lgkmcnt(0)" ::: "memory");                              \
    __builtin_amdgcn_sched_barrier(0);                                              \
    __builtin_amdgcn_s_setprio(1);                                                  \
    _Pragma("unroll") for (int mm = 0; mm < 2; ++mm)                                \
        _Pragma("unroll") for (int n = 0; n < 4; ++n)                               \
            _Pragma("unroll") for (int kk = 0; kk < 2; ++kk)                        \
                acc[2 * (p) + mm][n] = __builtin_amdgcn_mfma_f32_16x16x32_bf16(     \
                    afr[mm][kk], bfr[n][kk], acc[2 * (p) + mm][n], 0, 0, 0);        \
    __builtin_amdgcn_s_setprio(0);                                                  \
  } while (0)

#pragma unroll
    for (int n = 0; n < 4; ++n) { bfr[n][0] = ldB(b, n, 0); bfr[n][1] = ldB(b, n, 1); }
    afr[0][0] = ldA(b, 0, 0); afr[0][1] = ldA(b, 0, 1);
    afr[1][0] = ldA(b, 1, 0); afr[1][1] = ldA(b, 1, 1);
    if (pf) { stageA(nb, kt + 1, 0); stageB(nb, kt + 1, 0); }
    QUAD(0);
    __builtin_amdgcn_s_barrier();

    afr[0][0] = ldA(b, 2, 0); afr[0][1] = ldA(b, 2, 1);
    afr[1][0] = ldA(b, 3, 0); afr[1][1] = ldA(b, 3, 1);
    if (pf) { stageA(nb, kt + 1, 1); stageB(nb, kt + 1, 1); }
    QUAD(1);
    __builtin_amdgcn_s_barrier();

    afr[0][0] = ldA(b, 4, 0); afr[0][1] = ldA(b, 4, 1);
    afr[1][0] = ldA(b, 5, 0); afr[1][1] = ldA(b, 5, 1);
    QUAD(2);
    __builtin_amdgcn_s_barrier();

    afr[0][0] = ldA(b, 6, 0); afr[0][1] = ldA(b, 6, 1);
    afr[1][0] = ldA(b, 7, 0); afr[1][1] = ldA(b, 7, 1);
    QUAD(3);
    asm volatile("s_waitcnt vmcnt(0)" ::: "memory");
    __builtin_amdgcn_s_barrier();
#undef QUAD
  }

  // ---- epilogue ----
#pragma unroll
  for (int m = 0; m < 8; ++m)
#pragma unroll
    for (int n = 0; n < 4; ++n) {
      int rb = m0 + wr * 128 + m * 16 + (l >> 4) * 4;
      int col = n0 + wc * 64 + n * 16 + (l & 15);
      if constexpr (MODE == 0) {
        int proj = col >> 10;                     // 0=Q 1=K 2=V
        int slot = ((proj == 0) ? 1 : 0) ^ tz;
        int bh = ((rb >> 10) << 4) + ((col >> 6) & 15);
        int t0 = rb & 1023;
        int dc = col & 63;
        if (proj == 2) {
          // V^T, kv' interleaved within 32-blocks: pos = j + b4*4 + q2*8
          int newoff = (t0 >> 5) * 32 + ((t0 >> 2) & 3) * 8 + ((t0 >> 4) & 1) * 4;
          u16x4v pk;
#pragma unroll
          for (int j = 0; j < 4; ++j) pk[j] = f2bf(acc[m][n][j]);
          *reinterpret_cast<u16x4v*>(Vtg + (size_t)bh * 131072 +
                                     (size_t)(slot * 64 + dc) * 1024 + newoff) = pk;
        } else {
          // Q carries 0.5/sqrt(64) * log2(e) so softmax can use exp2 directly
          float sc = (proj == 0) ? 0.09016994f : 1.0f;
          u16* dstp = (proj ? Kb : Qb) + (size_t)bh * 131072 + (size_t)t0 * 128 + slot * 64 + dc;
#pragma unroll
          for (int j = 0; j < 4; ++j) dstp[(size_t)j * 128] = f2bf(acc[m][n][j] * sc);
        }
      } else {
        const float* bias = tz ? by : bx;
        float* dstp = out + (size_t)tz * BT * Dd;
        float bv = bias[col];
#pragma unroll
        for (int j = 0; j < 4; ++j)
          dstp[(size_t)(rb + j) * 1024 + col] = acc[m][n][j] + bv;
      }
    }
}

// ---------- flash attention: swapped QK^T, O^T = V^T @ P via mfma 16x16x16 ----------
// K LDS: Ks[4 dc][64 kv][32 d]  (64B rows, XOR-granule swizzle)
// V LDS: Vs[2 c][128 d][32 kv'] (64B rows, same swizzle; kv' pre-interleaved in global)
__global__ __launch_bounds__(256) void k_attn(const u16* __restrict__ Q,
                                              const u16* __restrict__ K,
                                              const u16* __restrict__ Vt,
                                              u16* __restrict__ O) {
  __shared__ alignas(16) u16 Ks[4 * 64 * 32];
  __shared__ alignas(16) u16 Vs[2 * 128 * 32];
  const int tid = threadIdx.x;
  const int l = tid & 63, w = tid >> 6;
  const int bid = blockIdx.x;
  const int xcd = bid & 7, li = bid >> 3;
  const int bh = xcd + 8 * (li >> 4);
  const int qx = li & 15;
  const int q0 = qx * 64 + w * 16;
  const size_t base = (size_t)bh * 131072;

  // Q fragments (B-operand of QK^T, col = q = l&15)
  bf16x8 qf[4];
#pragma unroll
  for (int dc = 0; dc < 4; ++dc)
    qf[dc] = *reinterpret_cast<const bf16x8*>(
        Q + base + (size_t)(q0 + (l & 15)) * 128 + dc * 32 + (l >> 4) * 8);

  // staging source pointers (kv0-invariant part)
  const u16* kp[4];
  const u16* vp[4];
#pragma unroll
  for (int r = 0; r < 4; ++r) {
    int idx = (r * 4 + w) * 64 + l;
    {
      int dc = idx >> 8, kv = (idx >> 2) & 63, pp = idx & 3, g = pp ^ ((kv >> 1) & 3);
      kp[r] = K + base + (size_t)kv * 128 + dc * 32 + g * 8;
    }
    {
      int c = idx >> 9, d = (idx >> 2) & 127, pp = idx & 3, g = pp ^ ((d >> 1) & 3);
      vp[r] = Vt + base + (size_t)d * 1024 + c * 32 + g * 8;
    }
  }
  // lane-constant LDS read offsets (elem units)
  const int koff = (l & 15) * 32 + (((l >> 4) ^ (((l & 15) >> 1) & 3))) * 8;
  const int voff = koff;  // same formula

  float m_run = -3e38f, l_run = 0.f;
  f32x4 Oa[8] = {};

  for (int kv0 = 0; kv0 < 1024; kv0 += 64) {
    // ---- stage K and V' ----
#pragma unroll
    for (int r = 0; r < 4; ++r) {
      int chunk = r * 4 + w;
      gload_lds16(kp[r] + (size_t)kv0 * 128, &Ks[chunk * 512 + l * 8]);
      gload_lds16(vp[r] + kv0, &Vs[chunk * 512 + l * 8]);
    }
    __syncthreads();

    // ---- swapped QK^T: S^T[kv][q], lane: q = l&15, kv = t*16 + (l>>4)*4 + j ----
    f32x4 S[4];
    __builtin_amdgcn_s_setprio(1);
#pragma unroll
    for (int t = 0; t < 4; ++t) {
      f32x4 s = {};
#pragma unroll
      for (int dc = 0; dc < 4; ++dc) {
        bf16x8 kb = *reinterpret_cast<const bf16x8*>(&Ks[dc * 2048 + t * 512 + koff]);
        s = __builtin_amdgcn_mfma_f32_16x16x32_bf16(kb, qf[dc], s, 0, 0, 0);
      }
      S[t] = s;
    }
    __builtin_amdgcn_s_setprio(0);

    // ---- online softmax (log2 domain), per-q = per-lane-column ----
    float mx = fmaxf(fmaxf(fmaxf(S[0][0], S[0][1]), fmaxf(S[0][2], S[0][3])),
                     fmaxf(fmaxf(S[1][0], S[1][1]), fmaxf(S[1][2], S[1][3])));
    float mx2 = fmaxf(fmaxf(fmaxf(S[2][0], S[2][1]), fmaxf(S[2][2], S[2][3])),
                      fmaxf(fmaxf(S[3][0], S[3][1]), fmaxf(S[3][2], S[3][3])));
    mx = fmaxf(mx, mx2);
    mx = fmaxf(mx, __shfl_xor(mx, 16));
    mx = fmaxf(mx, __shfl_xor(mx, 32));

    const int grow = __any(mx > m_run + 11.0f);   // defer-max (T13), log2 units
    float mn = grow ? fmaxf(m_run, mx) : m_run;
    float rs = 0.f;
#pragma unroll
    for (int t = 0; t < 4; ++t)
#pragma unroll
      for (int j = 0; j < 4; ++j) {
        S[t][j] = __builtin_exp2f(S[t][j] - mn);
        rs += S[t][j];
      }
    rs += __shfl_xor(rs, 16);
    rs += __shfl_xor(rs, 32);
    if (grow) {
      float alpha = __builtin_exp2f(m_run - mn);
      m_run = mn;
      l_run = alpha * l_run + rs;
#pragma unroll
      for (int n = 0; n < 8; ++n) Oa[n] *= alpha;
    } else {
      l_run += rs;
    }

    // ---- pack P tiles (B-frag of 16x16x16: k = (l>>4)*4 + j == S^T layout) ----
    union { u32 w2[2]; bf16x4 v; } pb[4];
#pragma unroll
    for (int t = 0; t < 4; ++t) {
      pb[t].w2[0] = cvtpk(S[t][0], S[t][1]);
      pb[t].w2[1] = cvtpk(S[t][2], S[t][3]);
    }

    // ---- PV: O^T += V^T @ P ----
    asm volatile("s_nop 1");   // VALU->MFMA read hazard guard (asm mfma path)
    __builtin_amdgcn_s_setprio(1);
#pragma unroll
    for (int c = 0; c < 2; ++c)
#pragma unroll
      for (int n = 0; n < 8; ++n) {
        bf16x8 av = *reinterpret_cast<const bf16x8*>(&Vs[c * 4096 + n * 512 + voff]);
        bf16x4 a0 = __builtin_shufflevector(av, av, 0, 1, 2, 3);
        bf16x4 a1 = __builtin_shufflevector(av, av, 4, 5, 6, 7);
        Oa[n] = MFMA16(a0, pb[2 * c].v, Oa[n]);
        Oa[n] = MFMA16(a1, pb[2 * c + 1].v, Oa[n]);
      }
    __builtin_amdgcn_s_setprio(0);
    __syncthreads();
  }
  asm volatile("s_nop 7");     // MFMA->VALU read hazard guard

  // ---- epilogue: lane holds O^T[d][q], q = l&15 ----
  float inv = 1.0f / l_run;
#pragma unroll
  for (int n = 0; n < 8; ++n) {
    u16x4v pk;
#pragma unroll
    for (int j = 0; j < 4; ++j) pk[j] = f2bf(Oa[n][j] * inv);
    *reinterpret_cast<u16x4v*>(
        O + base + (size_t)(q0 + (l & 15)) * 128 + n * 16 + (l >> 4) * 4) = pk;
  }
}

// ---------- launch ----------
extern "C" void kernel_launch(void* const* d_in, const int* in_sizes, int n_in,
                              void* d_out, int out_size, void* d_ws, size_t ws_size,
                              hipStream_t stream) {
  const float* x   = (const float*)d_in[0];
  const float* y   = (const float*)d_in[1];
  const float* Wq  = (const float*)d_in[2];
  const float* Wk  = (const float*)d_in[3];
  const float* Wv  = (const float*)d_in[4];
  const float* Wox = (const float*)d_in[5];
  const float* box = (const float*)d_in[6];
  const float* Woy = (const float*)d_in[7];
  const float* boy = (const float*)d_in[8];

  u16* ws = (u16*)d_ws;
  size_t off = 0;
  u16* xb  = ws + off; off += (size_t)BT * Dd;
  u16* yb  = ws + off; off += (size_t)BT * Dd;
  u16* Wqb = ws + off; off += (size_t)Dd * Dd;   // Wq,Wk,Wv contiguous
  u16* Wkb = ws + off; off += (size_t)Dd * Dd;
  u16* Wvb = ws + off; off += (size_t)Dd * Dd;
  u16* Woxb = ws + off; off += (size_t)Dd * Dd;  // Wox,Woy contiguous
  u16* Woyb = ws + off; off += (size_t)Dd * Dd;
  (void)Wkb; (void)Wvb; (void)Woyb;
  const size_t attn_elems = (size_t)Bb * Hh * Tt * 128;
  u16* Qb = ws + off; off += attn_elems;
  u16* Kb = ws + off; off += attn_elems;
  u16* Vb = ws + off; off += attn_elems;   // V^T [bh][128][1024], kv'-interleaved
  u16* Ob = ws + off; off += attn_elems;

  k_cvt2<<<dim3(1024, 1, 2), dim3(256), 0, stream>>>(x, y, xb, yb);
  k_cvt5<<<dim3(512, 1, 5), dim3(256), 0, stream>>>(Wq, Wk, Wv, Wox, Woy, Wqb);

  k_gemm256<0, 12, 32><<<dim3(768), dim3(512), 0, stream>>>(
      xb, yb, Wqb, Qb, Kb, Vb, nullptr, nullptr, nullptr);

  k_attn<<<dim3(2048), dim3(256), 0, stream>>>(Qb, Kb, Vb, Ob);

  k_gemm256<1, 4, 32><<<dim3(256), dim3(512), 0, stream>>>(
      Ob, nullptr, Woxb, nullptr, nullptr, nullptr, box, boy, (float*)d_out);
}

// Round 5
// 276.153 us; speedup vs baseline: 1.7456x; 1.0601x over previous
//
#include <hip/hip_runtime.h>
#include <stdint.h>

#define DEV __device__ __forceinline__

typedef __bf16 bf16x8 __attribute__((ext_vector_type(8)));
typedef __bf16 bf16x4 __attribute__((ext_vector_type(4)));
typedef short s16x4 __attribute__((ext_vector_type(4)));
typedef float f32x4 __attribute__((ext_vector_type(4)));
typedef unsigned short u16;
typedef u16 u16x4v __attribute__((ext_vector_type(4)));
typedef u16 u16x8 __attribute__((ext_vector_type(8)));
typedef uint32_t u32;

static constexpr int Bb = 8, Tt = 1024, Dd = 1024, Hh = 16;
static constexpr int BT = Bb * Tt;      // 8192

// ---------- helpers ----------
DEV u16 f2bf(float f) {
  u32 u = __float_as_uint(f);
  u32 r = (u + 0x7FFFu + ((u >> 16) & 1u)) >> 16;
  return (u16)r;
}
DEV u32 cvtpk(float lo, float hi) {
  u32 r;
  asm("v_cvt_pk_bf16_f32 %0, %1, %2" : "=v"(r) : "v"(lo), "v"(hi));
  return r;
}
DEV void gload_lds16(const void* g, void* lds) {
  __builtin_amdgcn_global_load_lds(
      (const __attribute__((address_space(1))) void*)g,
      (__attribute__((address_space(3))) void*)lds,
      16, 0, 0);
}
DEV f32x4 MFMA16(bf16x4 a, bf16x4 b, f32x4 c) {
#if __has_builtin(__builtin_amdgcn_mfma_f32_16x16x16_bf16)
  return __builtin_amdgcn_mfma_f32_16x16x16_bf16(a, b, c, 0, 0, 0);
#elif __has_builtin(__builtin_amdgcn_mfma_f32_16x16x16bf16_1k)
  union { bf16x4 b; s16x4 s; } ua, ub;
  ua.b = a; ub.b = b;
  return __builtin_amdgcn_mfma_f32_16x16x16bf16_1k(ua.s, ub.s, c, 0, 0, 0);
#else
  asm("v_mfma_f32_16x16x16_bf16 %0, %1, %2, %0" : "+v"(c) : "v"(a), "v"(b));
  return c;
#endif
}

// ---------- converts ----------
__global__ __launch_bounds__(256) void k_cvt2(const float* __restrict__ x,
                                              const float* __restrict__ y,
                                              u16* __restrict__ xb, u16* __restrict__ yb) {
  const float* src = blockIdx.z ? y : x;
  u16* dst = blockIdx.z ? yb : xb;
  const int n8 = BT * Dd / 8;
  int i = blockIdx.x * blockDim.x + threadIdx.x;
  int stride = gridDim.x * blockDim.x;
  for (; i < n8; i += stride) {
    const float4* p = reinterpret_cast<const float4*>(src) + (size_t)i * 2;
    float4 a = p[0], b = p[1];
    u16x8 o;
    o[0] = f2bf(a.x); o[1] = f2bf(a.y); o[2] = f2bf(a.z); o[3] = f2bf(a.w);
    o[4] = f2bf(b.x); o[5] = f2bf(b.y); o[6] = f2bf(b.z); o[7] = f2bf(b.w);
    reinterpret_cast<u16x8*>(dst)[i] = o;
  }
}

__global__ __launch_bounds__(256) void k_cvt5(const float* __restrict__ a0,
                                              const float* __restrict__ a1,
                                              const float* __restrict__ a2,
                                              const float* __restrict__ a3,
                                              const float* __restrict__ a4,
                                              u16* __restrict__ Wb) {
  int z = blockIdx.z;
  const float* src = (z == 0) ? a0 : (z == 1) ? a1 : (z == 2) ? a2 : (z == 3) ? a3 : a4;
  u16* dst = Wb + (size_t)z * (Dd * Dd);
  int i = blockIdx.x * blockDim.x + threadIdx.x;
  const float4* p = reinterpret_cast<const float4*>(src) + (size_t)i * 2;
  float4 a = p[0], b = p[1];
  u16x8 o;
  o[0] = f2bf(a.x); o[1] = f2bf(a.y); o[2] = f2bf(a.z); o[3] = f2bf(a.w);
  o[4] = f2bf(b.x); o[5] = f2bf(b.y); o[6] = f2bf(b.z); o[7] = f2bf(b.w);
  reinterpret_cast<u16x8*>(dst)[i] = o;
}

// ---------- 256x256-tile 8-wave 4-phase dbuf GEMM ----------
template <int MODE, int GX, int GY>
__global__ __launch_bounds__(512, 2) void k_gemm256(
    const u16* __restrict__ xb, const u16* __restrict__ yb,
    const u16* __restrict__ W0,
    u16* __restrict__ Qb, u16* __restrict__ Kb, u16* __restrict__ Vtg,
    const float* __restrict__ bx, const float* __restrict__ by,
    float* __restrict__ out) {
  __shared__ alignas(16) u16 As[2][256 * 64];
  __shared__ alignas(16) u16 Bs[2][256 * 64];
  const int tid = threadIdx.x;
  const int l = tid & 63, wid = tid >> 6;
  const int wr = wid >> 2, wc = wid & 3;

  constexpr int NWG = GX * GY * 2;
  const int d0b = blockIdx.x;
  const int wk = (d0b & 7) * (NWG / 8) + (d0b >> 3);
  const int tz = wk / (GX * GY);
  const int rr = wk % (GX * GY);
  const int ty = rr / GX, tx = rr % GX;
  const int m0 = ty * 256, n0 = tx * 256;

  const u16* Ag;
  const u16* Wg;
  if constexpr (MODE == 0) {
    Ag = tz ? yb : xb;
    Wg = W0;
  } else {
    Ag = xb + tz * 64;                       // xb carries Ob
    Wg = W0 + (size_t)tz * (Dd * Dd);
  }

  auto stageA = [&](int buf, int kt, int half) {
#pragma unroll
    for (int i = 0; i < 2; ++i) {
      int idx = i * 512 + tid;
      int row = idx >> 3, P = idx & 7, G = P ^ (row & 7);
      const u16* src;
      if constexpr (MODE == 0) {
        src = Ag + (size_t)(m0 + half * 128 + row) * 1024 + kt * 64 + G * 8;
      } else {
        int m = m0 + half * 128 + row;
        src = Ag + ((size_t)((m >> 10) * 16 + kt) * 1024 + (m & 1023)) * 128 + G * 8;
      }
      gload_lds16(src, &As[buf][half * 8192 + idx * 8]);
    }
  };
  auto stageB = [&](int buf, int kt, int half) {
#pragma unroll
    for (int i = 0; i < 2; ++i) {
      int idx = i * 512 + tid;
      int row = idx >> 3, P = idx & 7, G = P ^ (row & 7);
      gload_lds16(Wg + (size_t)(n0 + half * 128 + row) * 1024 + kt * 64 + G * 8,
                  &Bs[buf][half * 8192 + idx * 8]);
    }
  };
  auto ldA = [&](int b, int m, int kk) -> bf16x8 {
    int row = wr * 128 + m * 16 + (l & 15);
    int P = (kk * 4 + (l >> 4)) ^ (row & 7);
    return *reinterpret_cast<const bf16x8*>(&As[b][row * 64 + P * 8]);
  };
  auto ldB = [&](int b, int n, int kk) -> bf16x8 {
    int row = wc * 64 + n * 16 + (l & 15);
    int P = (kk * 4 + (l >> 4)) ^ (row & 7);
    return *reinterpret_cast<const bf16x8*>(&Bs[b][row * 64 + P * 8]);
  };

  f32x4 acc[8][4] = {};

  stageA(0, 0, 0); stageB(0, 0, 0); stageA(0, 0, 1); stageB(0, 0, 1);
  asm volatile("s_waitcnt vmcnt(0)" ::: "memory");
  __builtin_amdgcn_s_barrier();

  for (int kt = 0; kt < 16; ++kt) {
    const int b = kt & 1, nb = b ^ 1;
    const bool pf = (kt < 15);
    bf16x8 bfr[4][2], afr[2][2];

#define QUAD(p)                                                                     \
  do {                                                                              \
    __builtin_amdgcn_s_barrier();                                                   \
    asm volatile("s_waitcnt lgkmcnt(0)" ::: "memory");                              \
    __builtin_amdgcn_sched_barrier(0);                                              \
    __builtin_amdgcn_s_setprio(1);                                                  \
    _Pragma("unroll") for (int mm = 0; mm < 2; ++mm)                                \
        _Pragma("unroll") for (int n = 0; n < 4; ++n)                               \
            _Pragma("unroll") for (int kk = 0; kk < 2; ++kk)                        \
                acc[2 * (p) + mm][n] = __builtin_amdgcn_mfma_f32_16x16x32_bf16(     \
                    afr[mm][kk], bfr[n][kk], acc[2 * (p) + mm][n], 0, 0, 0);        \
    __builtin_amdgcn_s_setprio(0);                                                  \
  } while (0)

#pragma unroll
    for (int n = 0; n < 4; ++n) { bfr[n][0] = ldB(b, n, 0); bfr[n][1] = ldB(b, n, 1); }
    afr[0][0] = ldA(b, 0, 0); afr[0][1] = ldA(b, 0, 1);
    afr[1][0] = ldA(b, 1, 0); afr[1][1] = ldA(b, 1, 1);
    if (pf) { stageA(nb, kt + 1, 0); stageB(nb, kt + 1, 0); }
    QUAD(0);
    __builtin_amdgcn_s_barrier();

    afr[0][0] = ldA(b, 2, 0); afr[0][1] = ldA(b, 2, 1);
    afr[1][0] = ldA(b, 3, 0); afr[1][1] = ldA(b, 3, 1);
    if (pf) { stageA(nb, kt + 1, 1); stageB(nb, kt + 1, 1); }
    QUAD(1);
    __builtin_amdgcn_s_barrier();

    afr[0][0] = ldA(b, 4, 0); afr[0][1] = ldA(b, 4, 1);
    afr[1][0] = ldA(b, 5, 0); afr[1][1] = ldA(b, 5, 1);
    QUAD(2);
    __builtin_amdgcn_s_barrier();

    afr[0][0] = ldA(b, 6, 0); afr[0][1] = ldA(b, 6, 1);
    afr[1][0] = ldA(b, 7, 0); afr[1][1] = ldA(b, 7, 1);
    QUAD(3);
    asm volatile("s_waitcnt vmcnt(0)" ::: "memory");
    __builtin_amdgcn_s_barrier();
#undef QUAD
  }

  // ---- epilogue ----
#pragma unroll
  for (int m = 0; m < 8; ++m)
#pragma unroll
    for (int n = 0; n < 4; ++n) {
      int rb = m0 + wr * 128 + m * 16 + (l >> 4) * 4;
      int col = n0 + wc * 64 + n * 16 + (l & 15);
      if constexpr (MODE == 0) {
        int proj = col >> 10;                     // 0=Q 1=K 2=V
        int slot = ((proj == 0) ? 1 : 0) ^ tz;
        int bh = ((rb >> 10) << 4) + ((col >> 6) & 15);
        int t0 = rb & 1023;
        int dc = col & 63;
        if (proj == 2) {
          // V^T, kv' interleaved within 32-blocks: pos = j + b4*4 + q2*8
          int newoff = (t0 >> 5) * 32 + ((t0 >> 2) & 3) * 8 + ((t0 >> 4) & 1) * 4;
          u16x4v pk;
#pragma unroll
          for (int j = 0; j < 4; ++j) pk[j] = f2bf(acc[m][n][j]);
          *reinterpret_cast<u16x4v*>(Vtg + (size_t)bh * 131072 +
                                     (size_t)(slot * 64 + dc) * 1024 + newoff) = pk;
        } else {
          // Q carries 0.5/sqrt(64) * log2(e) so softmax can use exp2 directly
          float sc = (proj == 0) ? 0.09016994f : 1.0f;
          u16* dstp = (proj ? Kb : Qb) + (size_t)bh * 131072 + (size_t)t0 * 128 + slot * 64 + dc;
#pragma unroll
          for (int j = 0; j < 4; ++j) dstp[(size_t)j * 128] = f2bf(acc[m][n][j] * sc);
        }
      } else {
        const float* bias = tz ? by : bx;
        float* dstp = out + (size_t)tz * BT * Dd;
        float bv = bias[col];
#pragma unroll
        for (int j = 0; j < 4; ++j)
          dstp[(size_t)(rb + j) * 1024 + col] = acc[m][n][j] + bv;
      }
    }
}

// ---------- flash attention: 8 waves / 128 q-rows, dbuf 2-phase pipeline ----------
// K LDS: Ks[2][4 dc][64 kv][32 d]  (64B rows, XOR-granule swizzle)
// V LDS: Vs[2][2 c][128 d][32 kv'] (64B rows, same swizzle; kv' pre-interleaved)
__global__ __launch_bounds__(512, 4) void k_attn(const u16* __restrict__ Q,
                                                 const u16* __restrict__ K,
                                                 const u16* __restrict__ Vt,
                                                 u16* __restrict__ O) {
  __shared__ alignas(16) u16 Ks[2][8192];
  __shared__ alignas(16) u16 Vs[2][8192];
  const int tid = threadIdx.x;
  const int l = tid & 63, w = tid >> 6;
  const int bid = blockIdx.x;
  const int xcd = bid & 7, li = bid >> 3;
  const int bh = xcd + 8 * (li & 15);
  const int qblk = li >> 4;              // 0..7
  const int q0 = qblk * 128 + w * 16;
  const size_t base = (size_t)bh * 131072;

  // Q fragments (B-operand of QK^T, col = q = l&15)
  bf16x8 qf[4];
#pragma unroll
  for (int dc = 0; dc < 4; ++dc)
    qf[dc] = *reinterpret_cast<const bf16x8*>(
        Q + base + (size_t)(q0 + (l & 15)) * 128 + dc * 32 + (l >> 4) * 8);

  // staging source pointers (kv0-invariant): 2 K-granules + 2 V-granules / thread
  const u16* kp[2];
  const u16* vp[2];
#pragma unroll
  for (int i = 0; i < 2; ++i) {
    int idx = i * 512 + tid;
    {
      int dc = idx >> 8, kv = (idx >> 2) & 63, pp = idx & 3, g = pp ^ ((kv >> 1) & 3);
      kp[i] = K + base + (size_t)kv * 128 + dc * 32 + g * 8;
    }
    {
      int c = idx >> 9, d = (idx >> 2) & 127, pp = idx & 3, g = pp ^ ((d >> 1) & 3);
      vp[i] = Vt + base + (size_t)d * 1024 + c * 32 + g * 8;
    }
  }
  const int i0 = tid * 8, i1 = (512 + tid) * 8;    // LDS granule dests (elem units)

  // lane-constant LDS read offset (elem units)
  const int koff = (l & 15) * 32 + (((l >> 4) ^ (((l & 15) >> 1) & 3))) * 8;

  auto stage = [&](int buf, int kv0) {
    gload_lds16(kp[0] + (size_t)kv0 * 128, &Ks[buf][i0]);
    gload_lds16(kp[1] + (size_t)kv0 * 128, &Ks[buf][i1]);
    gload_lds16(vp[0] + kv0, &Vs[buf][i0]);
    gload_lds16(vp[1] + kv0, &Vs[buf][i1]);
  };

  float m_run = -3e38f, l_run = 0.f;
  f32x4 Oa[8] = {};

  stage(0, 0);
  __syncthreads();

  for (int t16 = 0; t16 < 16; ++t16) {
    const int cur = t16 & 1;
    if (t16 < 15) stage(cur ^ 1, (t16 + 1) * 64);   // prefetch next chunk

    // ---- swapped QK^T: S^T[kv][q], lane: q = l&15, kv = t*16 + (l>>4)*4 + j ----
    f32x4 S[4];
    __builtin_amdgcn_s_setprio(1);
#pragma unroll
    for (int t = 0; t < 4; ++t) {
      f32x4 s = {};
#pragma unroll
      for (int dc = 0; dc < 4; ++dc) {
        bf16x8 kb = *reinterpret_cast<const bf16x8*>(&Ks[cur][dc * 2048 + t * 512 + koff]);
        s = __builtin_amdgcn_mfma_f32_16x16x32_bf16(kb, qf[dc], s, 0, 0, 0);
      }
      S[t] = s;
    }
    __builtin_amdgcn_s_setprio(0);

    // ---- online softmax (log2 domain); defer-max: no cross-lane max unless grow ----
    float mxl = fmaxf(fmaxf(fmaxf(S[0][0], S[0][1]), fmaxf(S[0][2], S[0][3])),
                      fmaxf(fmaxf(S[1][0], S[1][1]), fmaxf(S[1][2], S[1][3])));
    float mx2 = fmaxf(fmaxf(fmaxf(S[2][0], S[2][1]), fmaxf(S[2][2], S[2][3])),
                      fmaxf(fmaxf(S[3][0], S[3][1]), fmaxf(S[3][2], S[3][3])));
    mxl = fmaxf(mxl, mx2);

    const int grow = __any(mxl > m_run + 11.0f);
    float mn = m_run, alpha = 1.0f;
    if (grow) {
      float mx = fmaxf(mxl, __shfl_xor(mxl, 16));
      mx = fmaxf(mx, __shfl_xor(mx, 32));
      mn = fmaxf(m_run, mx);
      alpha = __builtin_exp2f(m_run - mn);
      m_run = mn;
    }
    float rs = 0.f;
#pragma unroll
    for (int t = 0; t < 4; ++t)
#pragma unroll
      for (int j = 0; j < 4; ++j) {
        S[t][j] = __builtin_exp2f(S[t][j] - mn);
        rs += S[t][j];
      }
    rs += __shfl_xor(rs, 16);
    rs += __shfl_xor(rs, 32);
    if (grow) {
      l_run = alpha * l_run + rs;
#pragma unroll
      for (int n = 0; n < 8; ++n) Oa[n] *= alpha;
    } else {
      l_run += rs;
    }

    // ---- pack P tiles (B-frag of 16x16x16: k = (l>>4)*4 + j == S^T layout) ----
    union { u32 w2[2]; bf16x4 v; } pb[4];
#pragma unroll
    for (int t = 0; t < 4; ++t) {
      pb[t].w2[0] = cvtpk(S[t][0], S[t][1]);
      pb[t].w2[1] = cvtpk(S[t][2], S[t][3]);
    }

    // ---- PV: O^T += V^T @ P ----
    asm volatile("s_nop 1");
    __builtin_amdgcn_s_setprio(1);
#pragma unroll
    for (int c = 0; c < 2; ++c)
#pragma unroll
      for (int n = 0; n < 8; ++n) {
        bf16x8 av = *reinterpret_cast<const bf16x8*>(&Vs[cur][c * 4096 + n * 512 + koff]);
        bf16x4 a0 = __builtin_shufflevector(av, av, 0, 1, 2, 3);
        bf16x4 a1 = __builtin_shufflevector(av, av, 4, 5, 6, 7);
        Oa[n] = MFMA16(a0, pb[2 * c].v, Oa[n]);
        Oa[n] = MFMA16(a1, pb[2 * c + 1].v, Oa[n]);
      }
    __builtin_amdgcn_s_setprio(0);

    __syncthreads();   // drains prefetch vmcnt + syncs buffers
  }
  asm volatile("s_nop 7");

  // ---- epilogue: lane holds O^T[d][q], q = l&15 ----
  float inv = 1.0f / l_run;
#pragma unroll
  for (int n = 0; n < 8; ++n) {
    u16x4v pk;
#pragma unroll
    for (int j = 0; j < 4; ++j) pk[j] = f2bf(Oa[n][j] * inv);
    *reinterpret_cast<u16x4v*>(
        O + base + (size_t)(q0 + (l & 15)) * 128 + n * 16 + (l >> 4) * 4) = pk;
  }
}

// ---------- launch ----------
extern "C" void kernel_launch(void* const* d_in, const int* in_sizes, int n_in,
                              void* d_out, int out_size, void* d_ws, size_t ws_size,
                              hipStream_t stream) {
  const float* x   = (const float*)d_in[0];
  const float* y   = (const float*)d_in[1];
  const float* Wq  = (const float*)d_in[2];
  const float* Wk  = (const float*)d_in[3];
  const float* Wv  = (const float*)d_in[4];
  const float* Wox = (const float*)d_in[5];
  const float* box = (const float*)d_in[6];
  const float* Woy = (const float*)d_in[7];
  const float* boy = (const float*)d_in[8];

  u16* ws = (u16*)d_ws;
  size_t off = 0;
  u16* xb  = ws + off; off += (size_t)BT * Dd;
  u16* yb  = ws + off; off += (size_t)BT * Dd;
  u16* Wqb = ws + off; off += (size_t)Dd * Dd;   // Wq,Wk,Wv contiguous
  u16* Wkb = ws + off; off += (size_t)Dd * Dd;
  u16* Wvb = ws + off; off += (size_t)Dd * Dd;
  u16* Woxb = ws + off; off += (size_t)Dd * Dd;  // Wox,Woy contiguous
  u16* Woyb = ws + off; off += (size_t)Dd * Dd;
  (void)Wkb; (void)Wvb; (void)Woyb;
  const size_t attn_elems = (size_t)Bb * Hh * Tt * 128;
  u16* Qb = ws + off; off += attn_elems;
  u16* Kb = ws + off; off += attn_elems;
  u16* Vb = ws + off; off += attn_elems;   // V^T [bh][128][1024], kv'-interleaved
  u16* Ob = ws + off; off += attn_elems;

  k_cvt2<<<dim3(1024, 1, 2), dim3(256), 0, stream>>>(x, y, xb, yb);
  k_cvt5<<<dim3(512, 1, 5), dim3(256), 0, stream>>>(Wq, Wk, Wv, Wox, Woy, Wqb);

  k_gemm256<0, 12, 32><<<dim3(768), dim3(512), 0, stream>>>(
      xb, yb, Wqb, Qb, Kb, Vb, nullptr, nullptr, nullptr);

  k_attn<<<dim3(1024), dim3(512), 0, stream>>>(Qb, Kb, Vb, Ob);

  k_gemm256<1, 4, 32><<<dim3(256), dim3(512), 0, stream>>>(
      Ob, nullptr, Woxb, nullptr, nullptr, nullptr, box, boy, (float*)d_out);
}